// Round 8
// baseline (761.055 us; speedup 1.0000x reference)
//
#include <hip/hip_runtime.h>
#include <math.h>

#define REGC 1e-6f
#define LOG2PI 1.83787706640934534f
#define RESP_EPS 1.1920929e-6f

#define PART_K 561                  // packed upper-tri 528 + rows 32 + corner 1

typedef __attribute__((ext_vector_type(8))) short short8;
typedef __attribute__((ext_vector_type(4))) float f32x4;
typedef unsigned short ushort_t;
typedef unsigned int uint_t;

// device-scope (agent) coherent plain store/load: sc0+sc1, full streaming BW
#define STC(p, v) __hip_atomic_store((p), (v), __ATOMIC_RELAXED, __HIP_MEMORY_SCOPE_AGENT)
#define LDC(p)    __hip_atomic_load((p), __ATOMIC_RELAXED, __HIP_MEMORY_SCOPE_AGENT)

__device__ __forceinline__ ushort_t f2bf(float x) {
    uint_t u = __float_as_uint(x);
    uint_t r = (u + 0x7fffu + ((u >> 16) & 1u)) >> 16;   // RNE
    return (ushort_t)r;
}
__device__ __forceinline__ float bf2f(ushort_t h) {
    return __uint_as_float(((uint_t)h) << 16);
}
__device__ __forceinline__ f32x4 shx4(f32x4 v, int m) {
    f32x4 r;
#pragma unroll
    for (int i = 0; i < 4; ++i) r[i] = __shfl_xor(v[i], m);
    return r;
}
__device__ __forceinline__ f32x4 sel4(bool s, f32x4 b, f32x4 a) {
    f32x4 r;
#pragma unroll
    for (int i = 0; i < 4; ++i) r[i] = s ? b[i] : a[i];
    return r;
}
// r*x -> bf16 (round-half-up) packed A-frag; accumulates row sum.
__device__ __forceinline__ short8 pack_rx(const float* r8, const short8 bh, float& row) {
    uint_t u[8];
#pragma unroll
    for (int jj = 0; jj < 8; ++jj) {
        float av = r8[jj] * bf2f((ushort_t)bh[jj]);
        row += av;
        u[jj] = __float_as_uint(av) + 0x8000u;
    }
    short8 out;
    uint_t* o = (uint_t*)&out;
    o[0] = __builtin_amdgcn_perm(u[1], u[0], 0x07060302);
    o[1] = __builtin_amdgcn_perm(u[3], u[2], 0x07060302);
    o[2] = __builtin_amdgcn_perm(u[5], u[4], 0x07060302);
    o[3] = __builtin_amdgcn_perm(u[7], u[6], 0x07060302);
    return out;
}

// ---- fused prep: blocks [0,NCB) = xsplit; blocks [NCB,NCB+16) = prep0 + cnt zero ----
__global__ __launch_bounds__(256) void gmm_prep(const float* __restrict__ X,
                                                const float* __restrict__ w,
                                                const float* __restrict__ mu,
                                                const float* __restrict__ cov,
                                                ushort_t* __restrict__ Xh,
                                                ushort_t* __restrict__ Xl,
                                                ushort_t* __restrict__ XTH,
                                                ushort_t* __restrict__ Wh,
                                                ushort_t* __restrict__ Wl,
                                                float* __restrict__ Bv,
                                                float* __restrict__ Cc,
                                                int* __restrict__ cnt,
                                                int N, int NCB) {
    int t = threadIdx.x;
    if ((int)blockIdx.x < NCB) {
        // ---------------- xsplit body (R0-validated) ----------------
        int chunk = blockIdx.x;
        __shared__ float xsh[32][33];
        int s = t >> 3, q = t & 7;
        int n = chunk * 32 + s;
        float4 v = make_float4(0.f, 0.f, 0.f, 0.f);
        if (n < N) v = ((const float4*)(X + (size_t)n * 32))[q];
        float vv[4] = { v.x, v.y, v.z, v.w };
        xsh[s][q * 4 + 0] = v.x; xsh[s][q * 4 + 1] = v.y;
        xsh[s][q * 4 + 2] = v.z; xsh[s][q * 4 + 3] = v.w;
        if (n < N) {
            ushort_t h[4], l[4];
#pragma unroll
            for (int i = 0; i < 4; ++i) {
                h[i] = f2bf(vv[i]);
                l[i] = f2bf(vv[i] - bf2f(h[i]));
            }
            size_t o = (size_t)n * 32 + q * 4;
            *(uint2*)(Xh + o) = make_uint2((uint_t)h[0] | ((uint_t)h[1] << 16),
                                           (uint_t)h[2] | ((uint_t)h[3] << 16));
            *(uint2*)(Xl + o) = make_uint2((uint_t)l[0] | ((uint_t)l[1] << 16),
                                           (uint_t)l[2] | ((uint_t)l[3] << 16));
        }
        __syncthreads();
        int di = t >> 7;
        int lane = (t >> 1) & 63;
        int jj0 = (t & 1) * 4;
        int c = lane & 15, quad = lane >> 4;
        int d = di * 16 + c;
        ushort_t fh[4];
#pragma unroll
        for (int i = 0; i < 4; ++i) fh[i] = f2bf(xsh[quad * 8 + jj0 + i][d]);
        size_t fo = ((size_t)(chunk * 2 + di) * 64 + lane) * 8 + jj0;
        *(uint2*)(XTH + fo) = make_uint2((uint_t)fh[0] | ((uint_t)fh[1] << 16),
                                         (uint_t)fh[2] | ((uint_t)fh[3] << 16));
        return;
    }
    // ---------------- prep0 body (wave-synchronous, R5-validated) + cnt zero ----
    int k = (int)blockIdx.x - NCB;
    __shared__ float L[32][33];
    __shared__ float Ai[32][33];
    if (t >= 64) {
        if (k == 0 && t - 64 < 8) cnt[t - 64] = 0;   // ws may be poisoned
        return;
    }
    const float* cv = cov + (size_t)k * 1024;
    const float* muk = mu + (size_t)k * 32;
#pragma unroll
    for (int rep = 0; rep < 16; ++rep) {
        int idx = rep * 64 + t;
        int i = idx >> 5, j = idx & 31;
        L[i][j] = cv[idx] + (i == j ? REGC : 0.f);
    }
    asm volatile("" ::: "memory");
#pragma unroll
    for (int j = 0; j < 32; ++j) {
        float s = L[j][j];
#pragma unroll
        for (int p = 0; p < j; ++p) { float v = L[j][p]; s -= v * v; }
        float dj = sqrtf(s);
        if (t > j && t < 32) {
            float s2 = L[t][j];
#pragma unroll
            for (int p = 0; p < j; ++p) s2 -= L[t][p] * L[j][p];
            L[t][j] = s2 / dj;
        }
        if (t == j) L[j][j] = dj;
        asm volatile("" ::: "memory");
    }
    if (t < 32) {
        float ai[32];
#pragma unroll
        for (int r = 0; r < 32; ++r) {
            float s = (r == t) ? 1.f : 0.f;
#pragma unroll
            for (int p = 0; p < r; ++p) s -= L[r][p] * ai[p];
            ai[r] = s / L[r][r];
        }
#pragma unroll
        for (int r = 0; r < 32; ++r) Ai[r][t] = ai[r];
    }
    asm volatile("" ::: "memory");
#pragma unroll
    for (int rep = 0; rep < 16; ++rep) {
        int idx = rep * 64 + t;
        int i = idx >> 5, j = idx & 31;
        float v = Ai[i][j];
        ushort_t h = f2bf(v);
        Wh[(size_t)(k * 32 + i) * 32 + j] = h;
        Wl[(size_t)(k * 32 + i) * 32 + j] = f2bf(v - bf2f(h));
    }
    if (t < 32) {
        float s = 0.f;
#pragma unroll
        for (int j = 0; j < 32; ++j) s += Ai[t][j] * muk[j];
        Bv[k * 32 + t] = s;
    }
    float wsum = 0.f;
#pragma unroll
    for (int i = 0; i < 16; ++i) wsum += w[i];
    float lv = (t < 32) ? logf(L[t & 31][t & 31]) : 0.f;
#pragma unroll
    for (int off = 1; off < 32; off <<= 1) lv += __shfl_xor(lv, off);
    if (t == 0) Cc[k] = logf(w[k] / wsum) - 0.5f * 32.0f * LOG2PI - lv;
}

// ------- fused estep+moment+solve: 512 thr, 256 samples/block ---------------
// part written with plain device-coherent stores; blocks 0..15 spin on cnt[it],
// then reduce all MB partials for their component and solve.
// SAFETY: requires all MB blocks co-resident (MB=391 <= 2 blocks/CU * 256; R7-validated).
__global__ __launch_bounds__(512) __attribute__((amdgpu_waves_per_eu(4)))
void gmm_emstep(const ushort_t* __restrict__ Xh, const ushort_t* __restrict__ Xl,
                const ushort_t* __restrict__ XTH,
                ushort_t* __restrict__ Wh, ushort_t* __restrict__ Wl,
                float* __restrict__ Bv, float* __restrict__ Cc,
                float* __restrict__ part, int* __restrict__ cnt,
                int N, int MB, int it) {
    __shared__ float rsh[16][260];
    int t = threadIdx.x;
    int wave = t >> 6, lane = t & 63;
    int quad = lane >> 4, c = lane & 15;
    int bid = (int)blockIdx.x;

    int wstart0 = bid * 256 + wave * 32;
    bool dup = (wstart0 + 32 > N);
    int wst = dup ? ((N >= 32) ? N - 32 : 0) : wstart0;

    size_t xo0 = (size_t)(wst + c) * 32 + quad * 8;
    size_t xo1 = (size_t)(wst + 16 + c) * 32 + quad * 8;
    short8 ah0 = *(const short8*)(Xh + xo0);
    short8 al0 = *(const short8*)(Xl + xo0);
    short8 ah1 = *(const short8*)(Xh + xo1);
    short8 al1 = *(const short8*)(Xl + xo1);

    // ---- phase 1: estep (R0/R3-validated) ----
    {
        f32x4 p0[2], p1[2], p2[2], p3[2], fin[2];
#pragma unroll
        for (int k = 0; k < 16; ++k) {
            size_t w0 = (size_t)(k * 32 + c) * 32 + quad * 8;
            size_t w1 = w0 + 512;
            short8 bh0 = *(const short8*)(Wh + w0);
            short8 bl0 = *(const short8*)(Wl + w0);
            short8 bh1 = *(const short8*)(Wh + w1);
            short8 bl1 = *(const short8*)(Wl + w1);
            float bv0 = Bv[k * 32 + c];
            float bv1 = Bv[k * 32 + 16 + c];
#pragma unroll
            for (int tt = 0; tt < 2; ++tt) {
                short8 ah = tt ? ah1 : ah0;
                short8 al = tt ? al1 : al0;
                f32x4 a0 = {0.f, 0.f, 0.f, 0.f};
                f32x4 a1 = {0.f, 0.f, 0.f, 0.f};
                a0 = __builtin_amdgcn_mfma_f32_16x16x32_bf16(ah, bh0, a0, 0, 0, 0);
                a0 = __builtin_amdgcn_mfma_f32_16x16x32_bf16(ah, bl0, a0, 0, 0, 0);
                a0 = __builtin_amdgcn_mfma_f32_16x16x32_bf16(al, bh0, a0, 0, 0, 0);
                a1 = __builtin_amdgcn_mfma_f32_16x16x32_bf16(ah, bh1, a1, 0, 0, 0);
                a1 = __builtin_amdgcn_mfma_f32_16x16x32_bf16(ah, bl1, a1, 0, 0, 0);
                a1 = __builtin_amdgcn_mfma_f32_16x16x32_bf16(al, bh1, a1, 0, 0, 0);
                f32x4 ms;
#pragma unroll
                for (int r = 0; r < 4; ++r) {
                    float d0 = a0[r] - bv0;
                    float d1 = a1[r] - bv1;
                    ms[r] = fmaf(d0, d0, d1 * d1);
                }
                if ((k & 1) == 0) { p0[tt] = ms; }
                else {
                    f32x4 a = p0[tt] + shx4(p0[tt], 1);
                    f32x4 b = ms + shx4(ms, 1);
                    f32x4 v = sel4((c & 1) != 0, b, a);
                    if ((k & 2) == 0) { p1[tt] = v; }
                    else {
                        a = p1[tt] + shx4(p1[tt], 2); b = v + shx4(v, 2); v = sel4((c & 2) != 0, b, a);
                        if ((k & 4) == 0) { p2[tt] = v; }
                        else {
                            a = p2[tt] + shx4(p2[tt], 4); b = v + shx4(v, 4); v = sel4((c & 4) != 0, b, a);
                            if ((k & 8) == 0) { p3[tt] = v; }
                            else {
                                a = p3[tt] + shx4(p3[tt], 8); b = v + shx4(v, 8);
                                fin[tt] = sel4((c & 8) != 0, b, a);
                            }
                        }
                    }
                }
            }
        }
        float ccv = Cc[c];
#pragma unroll
        for (int tt = 0; tt < 2; ++tt) {
            f32x4 lp;
#pragma unroll
            for (int r = 0; r < 4; ++r) lp[r] = ccv - 0.5f * fin[tt][r];
            f32x4 mx = lp;
#pragma unroll
            for (int off = 1; off < 16; off <<= 1) {
                f32x4 s = shx4(mx, off);
#pragma unroll
                for (int r = 0; r < 4; ++r) mx[r] = fmaxf(mx[r], s[r]);
            }
            f32x4 e;
#pragma unroll
            for (int r = 0; r < 4; ++r) e[r] = __expf(lp[r] - mx[r]);
            f32x4 sm = e;
#pragma unroll
            for (int off = 1; off < 16; off <<= 1) sm = sm + shx4(sm, off);
            f32x4 sv;
#pragma unroll
            for (int r = 0; r < 4; ++r) sv[r] = dup ? 0.f : e[r] / sm[r];
            *(f32x4*)&rsh[c][wave * 32 + tt * 16 + quad * 4] = sv;
        }
    }
    __syncthreads();

    // ---- phase 2: moment (wave = 2 comps, 8 chunks, sym-packed, coherent stores) ----
    {
        f32x4 q00[2], q01[2], q11[2];
#pragma unroll
        for (int kk = 0; kk < 2; ++kk) {
            q00[kk] = (f32x4){0.f, 0.f, 0.f, 0.f};
            q01[kk] = (f32x4){0.f, 0.f, 0.f, 0.f};
            q11[kk] = (f32x4){0.f, 0.f, 0.f, 0.f};
        }
        float row0[2] = {0.f, 0.f}, row1[2] = {0.f, 0.f}, corner[2] = {0.f, 0.f};

#pragma unroll 2
        for (int ch = 0; ch < 8; ++ch) {
            size_t fb = (((size_t)(bid * 8 + ch)) * 128 + lane) * 8;
            short8 bh0 = *(const short8*)(XTH + fb);        // dims 0-15 frag
            short8 bh1 = *(const short8*)(XTH + fb + 512);  // dims 16-31 frag
#pragma unroll
            for (int kk = 0; kk < 2; ++kk) {
                int k = wave + kk * 8;
                float r8[8];
#pragma unroll
                for (int jj = 0; jj < 8; ++jj) r8[jj] = rsh[k][ch * 32 + quad * 8 + jj];
                corner[kk] += ((r8[0] + r8[1]) + (r8[2] + r8[3])) +
                              ((r8[4] + r8[5]) + (r8[6] + r8[7]));
                short8 a0 = pack_rx(r8, bh0, row0[kk]);
                short8 a1 = pack_rx(r8, bh1, row1[kk]);
                q00[kk] = __builtin_amdgcn_mfma_f32_16x16x32_bf16(a0, bh0, q00[kk], 0, 0, 0);
                q01[kk] = __builtin_amdgcn_mfma_f32_16x16x32_bf16(a0, bh1, q01[kk], 0, 0, 0);
                q11[kk] = __builtin_amdgcn_mfma_f32_16x16x32_bf16(a1, bh1, q11[kk], 0, 0, 0);
                // m10 dropped: symmetric, reconstructed from q01 in solve.
            }
        }
#pragma unroll
        for (int kk = 0; kk < 2; ++kk) {
            row0[kk] += __shfl_xor(row0[kk], 16);  row0[kk] += __shfl_xor(row0[kk], 32);
            row1[kk] += __shfl_xor(row1[kk], 16);  row1[kk] += __shfl_xor(row1[kk], 32);
            corner[kk] += __shfl_xor(corner[kk], 16);  corner[kk] += __shfl_xor(corner[kk], 32);

            int k = wave + kk * 8;
            float* pb = part + ((size_t)bid * 16 + k) * PART_K;
#pragma unroll
            for (int r = 0; r < 4; ++r) {
                int i = quad * 4 + r;
                int base = i * 32 - ((i * (i + 1)) >> 1);
                if (c >= i) STC(&pb[base + c], q00[kk][r]);          // upper diag quad
                STC(&pb[base + 16 + c], q01[kk][r]);                 // upper-right quad
                int i2 = 16 + i;
                if (c >= i) STC(&pb[i2 * 32 - ((i2 * (i2 + 1)) >> 1) + 16 + c],
                                q11[kk][r]);
            }
            if (quad == 0) {
                STC(&pb[528 + c], row0[kk]);
                STC(&pb[528 + 16 + c], row1[kk]);
            }
            if (lane == 0) STC(&pb[560], corner[kk]);
        }
    }
    __syncthreads();                 // drains vmcnt -> coherent stores complete
    if (t == 0)
        __hip_atomic_fetch_add(&cnt[it], 1, __ATOMIC_RELEASE, __HIP_MEMORY_SCOPE_AGENT);

    if (bid >= 16) return;

    // ---- phase 3 (blocks 0..15): wait for all partials, reduce + solve + prep ----
    if (t == 0) {
        while (__hip_atomic_load(&cnt[it], __ATOMIC_ACQUIRE, __HIP_MEMORY_SCOPE_AGENT) < MB)
            __builtin_amdgcn_s_sleep(8);
    }
    __syncthreads();

    int k = bid;
    float* Ssh   = &rsh[0][0];                   // LDS overlay (rsh dead now)
    float* Lsh   = Ssh + 576;                    // 32x33 = 1056
    float* Aish  = Lsh + 1056;
    float* meansh = Aish + 1056;

    for (int idx = t; idx < PART_K; idx += 512) {
        float s = 0.f;
        const float* sp = part + (size_t)k * PART_K + idx;
#pragma unroll 4
        for (int b = 0; b < MB; ++b)
            s += LDC(sp + (size_t)b * 16 * PART_K);
        Ssh[idx] = s;
    }
    __syncthreads();
    float nk = Ssh[560] + RESP_EPS;
    float inv = 1.f / nk;
    if (t < 32) meansh[t] = Ssh[528 + t] * inv;
    __syncthreads();
#pragma unroll
    for (int i0 = 0; i0 < 2; ++i0) {
        int i = i0 * 16 + (t >> 5), j = t & 31;
        int a = i < j ? i : j;
        int b2 = i < j ? j : i;
        float cv = Ssh[a * 32 - ((a * (a + 1)) >> 1) + b2];
        // M-step REGC + log_gauss REGC (reference applies both)
        Lsh[i * 33 + j] = cv * inv - meansh[i] * meansh[j] + ((i == j) ? 2.f * REGC : 0.f);
    }
    __syncthreads();
    if (t < 64) {
#pragma unroll
        for (int j = 0; j < 32; ++j) {
            float s = Lsh[j * 33 + j];
#pragma unroll
            for (int p = 0; p < j; ++p) { float v = Lsh[j * 33 + p]; s -= v * v; }
            float dj = sqrtf(s);
            if (t > j && t < 32) {
                float s2 = Lsh[t * 33 + j];
#pragma unroll
                for (int p = 0; p < j; ++p) s2 -= Lsh[t * 33 + p] * Lsh[j * 33 + p];
                Lsh[t * 33 + j] = s2 / dj;
            }
            if (t == j) Lsh[j * 33 + j] = dj;
            asm volatile("" ::: "memory");
        }
        if (t < 32) {
            float ai[32];
#pragma unroll
            for (int r = 0; r < 32; ++r) {
                float s = (r == t) ? 1.f : 0.f;
#pragma unroll
                for (int p = 0; p < r; ++p) s -= Lsh[r * 33 + p] * ai[p];
                ai[r] = s / Lsh[r * 33 + r];
            }
#pragma unroll
            for (int r = 0; r < 32; ++r) Aish[r * 33 + t] = ai[r];
        }
    }
    __syncthreads();
#pragma unroll
    for (int i0 = 0; i0 < 2; ++i0) {
        int i = i0 * 16 + (t >> 5), j = t & 31;
        float v = Aish[i * 33 + j];
        ushort_t h = f2bf(v);
        Wh[(size_t)(k * 32 + i) * 32 + j] = h;
        Wl[(size_t)(k * 32 + i) * 32 + j] = f2bf(v - bf2f(h));
    }
    if (t < 32) {
        float s = 0.f;
#pragma unroll
        for (int j = 0; j < 32; ++j) s += Aish[t * 33 + j] * meansh[j];
        Bv[k * 32 + t] = s;
    }
    float lv = (t < 32) ? logf(Lsh[(t & 31) * 33 + (t & 31)]) : 0.f;
#pragma unroll
    for (int off = 1; off < 32; off <<= 1) lv += __shfl_xor(lv, off);
    if (t == 0) Cc[k] = logf(nk / (float)N) - 0.5f * 32.0f * LOG2PI - lv;
}

// ---------------- final estep: log-likelihood only (R3-validated) ----------------
__global__ __launch_bounds__(256, 2) void gmm_estep_fin(const ushort_t* __restrict__ Xh,
                                                        const ushort_t* __restrict__ Xl,
                                                        const ushort_t* __restrict__ Wh,
                                                        const ushort_t* __restrict__ Wl,
                                                        const float* __restrict__ Bv,
                                                        const float* __restrict__ Cc,
                                                        float* __restrict__ out,
                                                        int N) {
    int t = threadIdx.x;
    int wave = t >> 6, lane = t & 63;
    int quad = lane >> 4, c = lane & 15;
    int wstart = (blockIdx.x * 4 + wave) * 32;
    if (wstart + 32 > N) wstart = (N >= 32) ? (N - 32) : 0;
    bool al4 = ((N & 3) == 0);

    size_t xo0 = (size_t)(wstart + c) * 32 + quad * 8;
    size_t xo1 = (size_t)(wstart + 16 + c) * 32 + quad * 8;
    short8 ah0 = *(const short8*)(Xh + xo0);
    short8 al0 = *(const short8*)(Xl + xo0);
    short8 ah1 = *(const short8*)(Xh + xo1);
    short8 al1 = *(const short8*)(Xl + xo1);

    f32x4 p0[2], p1[2], p2[2], p3[2], fin[2];
#pragma unroll
    for (int k = 0; k < 16; ++k) {
        size_t w0 = (size_t)(k * 32 + c) * 32 + quad * 8;
        size_t w1 = w0 + 512;
        short8 bh0 = *(const short8*)(Wh + w0);
        short8 bl0 = *(const short8*)(Wl + w0);
        short8 bh1 = *(const short8*)(Wh + w1);
        short8 bl1 = *(const short8*)(Wl + w1);
        float bv0 = Bv[k * 32 + c];
        float bv1 = Bv[k * 32 + 16 + c];
#pragma unroll
        for (int tt = 0; tt < 2; ++tt) {
            short8 ah = tt ? ah1 : ah0;
            short8 al = tt ? al1 : al0;
            f32x4 a0 = {0.f, 0.f, 0.f, 0.f};
            f32x4 a1 = {0.f, 0.f, 0.f, 0.f};
            a0 = __builtin_amdgcn_mfma_f32_16x16x32_bf16(ah, bh0, a0, 0, 0, 0);
            a0 = __builtin_amdgcn_mfma_f32_16x16x32_bf16(ah, bl0, a0, 0, 0, 0);
            a0 = __builtin_amdgcn_mfma_f32_16x16x32_bf16(al, bh0, a0, 0, 0, 0);
            a1 = __builtin_amdgcn_mfma_f32_16x16x32_bf16(ah, bh1, a1, 0, 0, 0);
            a1 = __builtin_amdgcn_mfma_f32_16x16x32_bf16(ah, bl1, a1, 0, 0, 0);
            a1 = __builtin_amdgcn_mfma_f32_16x16x32_bf16(al, bh1, a1, 0, 0, 0);
            f32x4 ms;
#pragma unroll
            for (int r = 0; r < 4; ++r) {
                float d0 = a0[r] - bv0;
                float d1 = a1[r] - bv1;
                ms[r] = fmaf(d0, d0, d1 * d1);
            }
            if ((k & 1) == 0) { p0[tt] = ms; }
            else {
                f32x4 a = p0[tt] + shx4(p0[tt], 1);
                f32x4 b = ms + shx4(ms, 1);
                f32x4 v = sel4((c & 1) != 0, b, a);
                if ((k & 2) == 0) { p1[tt] = v; }
                else {
                    a = p1[tt] + shx4(p1[tt], 2); b = v + shx4(v, 2); v = sel4((c & 2) != 0, b, a);
                    if ((k & 4) == 0) { p2[tt] = v; }
                    else {
                        a = p2[tt] + shx4(p2[tt], 4); b = v + shx4(v, 4); v = sel4((c & 4) != 0, b, a);
                        if ((k & 8) == 0) { p3[tt] = v; }
                        else {
                            a = p3[tt] + shx4(p3[tt], 8); b = v + shx4(v, 8);
                            fin[tt] = sel4((c & 8) != 0, b, a);
                        }
                    }
                }
            }
        }
    }
    float ccv = Cc[c];
#pragma unroll
    for (int tt = 0; tt < 2; ++tt) {
        f32x4 lp;
#pragma unroll
        for (int r = 0; r < 4; ++r) lp[r] = ccv - 0.5f * fin[tt][r];
        f32x4 mx = lp;
#pragma unroll
        for (int off = 1; off < 16; off <<= 1) {
            f32x4 s = shx4(mx, off);
#pragma unroll
            for (int r = 0; r < 4; ++r) mx[r] = fmaxf(mx[r], s[r]);
        }
        f32x4 e;
#pragma unroll
        for (int r = 0; r < 4; ++r) e[r] = __expf(lp[r] - mx[r]);
        f32x4 sm = e;
#pragma unroll
        for (int off = 1; off < 16; off <<= 1) sm = sm + shx4(sm, off);
        if (c == 0) {
            int nb = wstart + tt * 16 + quad * 4;
            f32x4 o;
#pragma unroll
            for (int r = 0; r < 4; ++r) o[r] = mx[r] + __logf(sm[r]);
            if (al4) *(f32x4*)(out + nb) = o;
            else { for (int r = 0; r < 4; ++r) out[nb + r] = o[r]; }
        }
    }
}

// ================================== launcher ==================================
extern "C" void kernel_launch(void* const* d_in, const int* in_sizes, int n_in,
                              void* d_out, int out_size, void* d_ws, size_t ws_size,
                              hipStream_t stream) {
    const float* X   = (const float*)d_in[0];
    const float* w   = (const float*)d_in[1];
    const float* mu  = (const float*)d_in[2];
    const float* cov = (const float*)d_in[3];
    const int NITER = 5;
    int N = in_sizes[0] / 32;
    int MB = (N + 255) / 256;        // emstep blocks (256 samples each)
    int NCB = MB * 8;                // staged chunks (zero-padded past N)

    float* ws = (float*)d_ws;
    float*    Bv = ws;                               // 512
    float*    Cc = ws + 512;                         // 16 (+pad to 528)
    ushort_t* Wh = (ushort_t*)(ws + 528);            // 8192 f
    ushort_t* Wl = (ushort_t*)(ws + 8720);           // 8192 f -> 16912
    ushort_t* Xh = (ushort_t*)(ws + 16912);          // 16N f
    ushort_t* Xl = (ushort_t*)(ws + 16912 + (size_t)16 * N);
    size_t xt0 = 16912 + (size_t)32 * N;
    size_t XTHf = (size_t)NCB * 512;                 // XTH floats
    ushort_t* XTH = (ushort_t*)(ws + xt0);
    float*  part = ws + xt0 + XTHf;                  // MB*16*PART_K floats
    int*    cnt  = (int*)(part + (size_t)MB * 16 * PART_K);  // 8 ints

    float* out = (float*)d_out;

    int eblocks = ((N + 31) / 32 + 3) / 4;

    gmm_prep<<<NCB + 16, 256, 0, stream>>>(X, w, mu, cov, Xh, Xl, XTH, Wh, Wl,
                                           Bv, Cc, cnt, N, NCB);

    for (int it = 0; it < NITER; ++it)
        gmm_emstep<<<MB, 512, 0, stream>>>(Xh, Xl, XTH, Wh, Wl, Bv, Cc, part, cnt,
                                           N, MB, it);

    gmm_estep_fin<<<eblocks, 256, 0, stream>>>(Xh, Xl, Wh, Wl, Bv, Cc, out, N);
}

// Round 9
// 465.776 us; speedup vs baseline: 1.6340x; 1.6340x over previous
//
#include <hip/hip_runtime.h>
#include <math.h>

#define REGC 1e-6f
#define LOG2PI 1.83787706640934534f
#define RESP_EPS 1.1920929e-6f

#define PART_K 561                  // packed upper-tri 528 + rows 32 + corner 1
#define RS 16                       // reduce groups

typedef __attribute__((ext_vector_type(8))) short short8;
typedef __attribute__((ext_vector_type(4))) float f32x4;
typedef unsigned short ushort_t;
typedef unsigned int uint_t;

// device-scope coherent ops — ONLY for the tiny part2/cnt handoff (0.57 MB).
#define STC(p, v) __hip_atomic_store((p), (v), __ATOMIC_RELAXED, __HIP_MEMORY_SCOPE_AGENT)
#define LDC(p)    __hip_atomic_load((p), __ATOMIC_RELAXED, __HIP_MEMORY_SCOPE_AGENT)

__device__ __forceinline__ ushort_t f2bf(float x) {
    uint_t u = __float_as_uint(x);
    uint_t r = (u + 0x7fffu + ((u >> 16) & 1u)) >> 16;   // RNE
    return (ushort_t)r;
}
__device__ __forceinline__ float bf2f(ushort_t h) {
    return __uint_as_float(((uint_t)h) << 16);
}
__device__ __forceinline__ f32x4 shx4(f32x4 v, int m) {
    f32x4 r;
#pragma unroll
    for (int i = 0; i < 4; ++i) r[i] = __shfl_xor(v[i], m);
    return r;
}
__device__ __forceinline__ f32x4 sel4(bool s, f32x4 b, f32x4 a) {
    f32x4 r;
#pragma unroll
    for (int i = 0; i < 4; ++i) r[i] = s ? b[i] : a[i];
    return r;
}
// r*x -> bf16 (round-half-up) packed A-frag; accumulates row sum.
__device__ __forceinline__ short8 pack_rx(const float* r8, const short8 bh, float& row) {
    uint_t u[8];
#pragma unroll
    for (int jj = 0; jj < 8; ++jj) {
        float av = r8[jj] * bf2f((ushort_t)bh[jj]);
        row += av;
        u[jj] = __float_as_uint(av) + 0x8000u;
    }
    short8 out;
    uint_t* o = (uint_t*)&out;
    o[0] = __builtin_amdgcn_perm(u[1], u[0], 0x07060302);
    o[1] = __builtin_amdgcn_perm(u[3], u[2], 0x07060302);
    o[2] = __builtin_amdgcn_perm(u[5], u[4], 0x07060302);
    o[3] = __builtin_amdgcn_perm(u[7], u[6], 0x07060302);
    return out;
}

// ---- fused prep: blocks [0,NCB) = xsplit; blocks [NCB,NCB+16) = prep0 + cnt zero ----
__global__ __launch_bounds__(256) void gmm_prep(const float* __restrict__ X,
                                                const float* __restrict__ w,
                                                const float* __restrict__ mu,
                                                const float* __restrict__ cov,
                                                ushort_t* __restrict__ Xh,
                                                ushort_t* __restrict__ Xl,
                                                ushort_t* __restrict__ XTH,
                                                ushort_t* __restrict__ Wh,
                                                ushort_t* __restrict__ Wl,
                                                float* __restrict__ Bv,
                                                float* __restrict__ Cc,
                                                int* __restrict__ cnt,
                                                int N, int NCB) {
    int t = threadIdx.x;
    if ((int)blockIdx.x < NCB) {
        // ---------------- xsplit body (R0-validated) ----------------
        int chunk = blockIdx.x;
        __shared__ float xsh[32][33];
        int s = t >> 3, q = t & 7;
        int n = chunk * 32 + s;
        float4 v = make_float4(0.f, 0.f, 0.f, 0.f);
        if (n < N) v = ((const float4*)(X + (size_t)n * 32))[q];
        float vv[4] = { v.x, v.y, v.z, v.w };
        xsh[s][q * 4 + 0] = v.x; xsh[s][q * 4 + 1] = v.y;
        xsh[s][q * 4 + 2] = v.z; xsh[s][q * 4 + 3] = v.w;
        if (n < N) {
            ushort_t h[4], l[4];
#pragma unroll
            for (int i = 0; i < 4; ++i) {
                h[i] = f2bf(vv[i]);
                l[i] = f2bf(vv[i] - bf2f(h[i]));
            }
            size_t o = (size_t)n * 32 + q * 4;
            *(uint2*)(Xh + o) = make_uint2((uint_t)h[0] | ((uint_t)h[1] << 16),
                                           (uint_t)h[2] | ((uint_t)h[3] << 16));
            *(uint2*)(Xl + o) = make_uint2((uint_t)l[0] | ((uint_t)l[1] << 16),
                                           (uint_t)l[2] | ((uint_t)l[3] << 16));
        }
        __syncthreads();
        int di = t >> 7;
        int lane = (t >> 1) & 63;
        int jj0 = (t & 1) * 4;
        int c = lane & 15, quad = lane >> 4;
        int d = di * 16 + c;
        ushort_t fh[4];
#pragma unroll
        for (int i = 0; i < 4; ++i) fh[i] = f2bf(xsh[quad * 8 + jj0 + i][d]);
        size_t fo = ((size_t)(chunk * 2 + di) * 64 + lane) * 8 + jj0;
        *(uint2*)(XTH + fo) = make_uint2((uint_t)fh[0] | ((uint_t)fh[1] << 16),
                                         (uint_t)fh[2] | ((uint_t)fh[3] << 16));
        return;
    }
    // ---------------- prep0 body (wave-synchronous, R5-validated) + cnt zero ----
    int k = (int)blockIdx.x - NCB;
    __shared__ float L[32][33];
    __shared__ float Ai[32][33];
    if (t >= 64) {
        if (k == 0 && t - 64 < 8) cnt[t - 64] = 0;   // ws may be poisoned
        return;
    }
    const float* cv = cov + (size_t)k * 1024;
    const float* muk = mu + (size_t)k * 32;
#pragma unroll
    for (int rep = 0; rep < 16; ++rep) {
        int idx = rep * 64 + t;
        int i = idx >> 5, j = idx & 31;
        L[i][j] = cv[idx] + (i == j ? REGC : 0.f);
    }
    asm volatile("" ::: "memory");
#pragma unroll
    for (int j = 0; j < 32; ++j) {
        float s = L[j][j];
#pragma unroll
        for (int p = 0; p < j; ++p) { float v = L[j][p]; s -= v * v; }
        float dj = sqrtf(s);
        if (t > j && t < 32) {
            float s2 = L[t][j];
#pragma unroll
            for (int p = 0; p < j; ++p) s2 -= L[t][p] * L[j][p];
            L[t][j] = s2 / dj;
        }
        if (t == j) L[j][j] = dj;
        asm volatile("" ::: "memory");
    }
    if (t < 32) {
        float ai[32];
#pragma unroll
        for (int r = 0; r < 32; ++r) {
            float s = (r == t) ? 1.f : 0.f;
#pragma unroll
            for (int p = 0; p < r; ++p) s -= L[r][p] * ai[p];
            ai[r] = s / L[r][r];
        }
#pragma unroll
        for (int r = 0; r < 32; ++r) Ai[r][t] = ai[r];
    }
    asm volatile("" ::: "memory");
#pragma unroll
    for (int rep = 0; rep < 16; ++rep) {
        int idx = rep * 64 + t;
        int i = idx >> 5, j = idx & 31;
        float v = Ai[i][j];
        ushort_t h = f2bf(v);
        Wh[(size_t)(k * 32 + i) * 32 + j] = h;
        Wl[(size_t)(k * 32 + i) * 32 + j] = f2bf(v - bf2f(h));
    }
    if (t < 32) {
        float s = 0.f;
#pragma unroll
        for (int j = 0; j < 32; ++j) s += Ai[t][j] * muk[j];
        Bv[k * 32 + t] = s;
    }
    float wsum = 0.f;
#pragma unroll
    for (int i = 0; i < 16; ++i) wsum += w[i];
    float lv = (t < 32) ? logf(L[t & 31][t & 31]) : 0.f;
#pragma unroll
    for (int off = 1; off < 32; off <<= 1) lv += __shfl_xor(lv, off);
    if (t == 0) Cc[k] = logf(w[k] / wsum) - 0.5f * 32.0f * LOG2PI - lv;
}

// ------- fused estep+moment: R3-validated body, waves_per_eu(3) (VGPR cap ~168) -----
// Grid supplies only ~3 waves/SIMD (3128 waves / 1024 SIMDs), so VGPR up to ~168
// costs no effective occupancy; frees the allocator to batch loads / pipeline deeper.
__global__ __launch_bounds__(512) __attribute__((amdgpu_waves_per_eu(3)))
void gmm_emstep(const ushort_t* __restrict__ Xh, const ushort_t* __restrict__ Xl,
                const ushort_t* __restrict__ XTH,
                const ushort_t* __restrict__ Wh, const ushort_t* __restrict__ Wl,
                const float* __restrict__ Bv, const float* __restrict__ Cc,
                float* __restrict__ part, int N) {
    __shared__ float rsh[16][260];
    int t = threadIdx.x;
    int wave = t >> 6, lane = t & 63;
    int quad = lane >> 4, c = lane & 15;
    int bid = (int)blockIdx.x;

    int wstart0 = bid * 256 + wave * 32;
    bool dup = (wstart0 + 32 > N);
    int wst = dup ? ((N >= 32) ? N - 32 : 0) : wstart0;

    size_t xo0 = (size_t)(wst + c) * 32 + quad * 8;
    size_t xo1 = (size_t)(wst + 16 + c) * 32 + quad * 8;
    short8 ah0 = *(const short8*)(Xh + xo0);
    short8 al0 = *(const short8*)(Xl + xo0);
    short8 ah1 = *(const short8*)(Xh + xo1);
    short8 al1 = *(const short8*)(Xl + xo1);

    // ---- phase 1: estep (R0/R3-validated) ----
    {
        f32x4 p0[2], p1[2], p2[2], p3[2], fin[2];
#pragma unroll
        for (int k = 0; k < 16; ++k) {
            size_t w0 = (size_t)(k * 32 + c) * 32 + quad * 8;
            size_t w1 = w0 + 512;
            short8 bh0 = *(const short8*)(Wh + w0);
            short8 bl0 = *(const short8*)(Wl + w0);
            short8 bh1 = *(const short8*)(Wh + w1);
            short8 bl1 = *(const short8*)(Wl + w1);
            float bv0 = Bv[k * 32 + c];
            float bv1 = Bv[k * 32 + 16 + c];
#pragma unroll
            for (int tt = 0; tt < 2; ++tt) {
                short8 ah = tt ? ah1 : ah0;
                short8 al = tt ? al1 : al0;
                f32x4 a0 = {0.f, 0.f, 0.f, 0.f};
                f32x4 a1 = {0.f, 0.f, 0.f, 0.f};
                a0 = __builtin_amdgcn_mfma_f32_16x16x32_bf16(ah, bh0, a0, 0, 0, 0);
                a0 = __builtin_amdgcn_mfma_f32_16x16x32_bf16(ah, bl0, a0, 0, 0, 0);
                a0 = __builtin_amdgcn_mfma_f32_16x16x32_bf16(al, bh0, a0, 0, 0, 0);
                a1 = __builtin_amdgcn_mfma_f32_16x16x32_bf16(ah, bh1, a1, 0, 0, 0);
                a1 = __builtin_amdgcn_mfma_f32_16x16x32_bf16(ah, bl1, a1, 0, 0, 0);
                a1 = __builtin_amdgcn_mfma_f32_16x16x32_bf16(al, bh1, a1, 0, 0, 0);
                f32x4 ms;
#pragma unroll
                for (int r = 0; r < 4; ++r) {
                    float d0 = a0[r] - bv0;
                    float d1 = a1[r] - bv1;
                    ms[r] = fmaf(d0, d0, d1 * d1);
                }
                if ((k & 1) == 0) { p0[tt] = ms; }
                else {
                    f32x4 a = p0[tt] + shx4(p0[tt], 1);
                    f32x4 b = ms + shx4(ms, 1);
                    f32x4 v = sel4((c & 1) != 0, b, a);
                    if ((k & 2) == 0) { p1[tt] = v; }
                    else {
                        a = p1[tt] + shx4(p1[tt], 2); b = v + shx4(v, 2); v = sel4((c & 2) != 0, b, a);
                        if ((k & 4) == 0) { p2[tt] = v; }
                        else {
                            a = p2[tt] + shx4(p2[tt], 4); b = v + shx4(v, 4); v = sel4((c & 4) != 0, b, a);
                            if ((k & 8) == 0) { p3[tt] = v; }
                            else {
                                a = p3[tt] + shx4(p3[tt], 8); b = v + shx4(v, 8);
                                fin[tt] = sel4((c & 8) != 0, b, a);
                            }
                        }
                    }
                }
            }
        }
        float ccv = Cc[c];
#pragma unroll
        for (int tt = 0; tt < 2; ++tt) {
            f32x4 lp;
#pragma unroll
            for (int r = 0; r < 4; ++r) lp[r] = ccv - 0.5f * fin[tt][r];
            f32x4 mx = lp;
#pragma unroll
            for (int off = 1; off < 16; off <<= 1) {
                f32x4 s = shx4(mx, off);
#pragma unroll
                for (int r = 0; r < 4; ++r) mx[r] = fmaxf(mx[r], s[r]);
            }
            f32x4 e;
#pragma unroll
            for (int r = 0; r < 4; ++r) e[r] = __expf(lp[r] - mx[r]);
            f32x4 sm = e;
#pragma unroll
            for (int off = 1; off < 16; off <<= 1) sm = sm + shx4(sm, off);
            f32x4 sv;
#pragma unroll
            for (int r = 0; r < 4; ++r) sv[r] = dup ? 0.f : e[r] / sm[r];
            *(f32x4*)&rsh[c][wave * 32 + tt * 16 + quad * 4] = sv;
        }
    }
    __syncthreads();

    // ---- phase 2: moment (wave = 2 comps, 8 chunks, sym-packed, plain stores) ----
    {
        f32x4 q00[2], q01[2], q11[2];
#pragma unroll
        for (int kk = 0; kk < 2; ++kk) {
            q00[kk] = (f32x4){0.f, 0.f, 0.f, 0.f};
            q01[kk] = (f32x4){0.f, 0.f, 0.f, 0.f};
            q11[kk] = (f32x4){0.f, 0.f, 0.f, 0.f};
        }
        float row0[2] = {0.f, 0.f}, row1[2] = {0.f, 0.f}, corner[2] = {0.f, 0.f};

#pragma unroll 2
        for (int ch = 0; ch < 8; ++ch) {
            size_t fb = (((size_t)(bid * 8 + ch)) * 128 + lane) * 8;
            short8 bh0 = *(const short8*)(XTH + fb);        // dims 0-15 frag
            short8 bh1 = *(const short8*)(XTH + fb + 512);  // dims 16-31 frag
#pragma unroll
            for (int kk = 0; kk < 2; ++kk) {
                int k = wave + kk * 8;
                float r8[8];
#pragma unroll
                for (int jj = 0; jj < 8; ++jj) r8[jj] = rsh[k][ch * 32 + quad * 8 + jj];
                corner[kk] += ((r8[0] + r8[1]) + (r8[2] + r8[3])) +
                              ((r8[4] + r8[5]) + (r8[6] + r8[7]));
                short8 a0 = pack_rx(r8, bh0, row0[kk]);
                short8 a1 = pack_rx(r8, bh1, row1[kk]);
                q00[kk] = __builtin_amdgcn_mfma_f32_16x16x32_bf16(a0, bh0, q00[kk], 0, 0, 0);
                q01[kk] = __builtin_amdgcn_mfma_f32_16x16x32_bf16(a0, bh1, q01[kk], 0, 0, 0);
                q11[kk] = __builtin_amdgcn_mfma_f32_16x16x32_bf16(a1, bh1, q11[kk], 0, 0, 0);
                // m10 dropped: symmetric, reconstructed from q01 in redsolve.
            }
        }
#pragma unroll
        for (int kk = 0; kk < 2; ++kk) {
            row0[kk] += __shfl_xor(row0[kk], 16);  row0[kk] += __shfl_xor(row0[kk], 32);
            row1[kk] += __shfl_xor(row1[kk], 16);  row1[kk] += __shfl_xor(row1[kk], 32);
            corner[kk] += __shfl_xor(corner[kk], 16);  corner[kk] += __shfl_xor(corner[kk], 32);

            int k = wave + kk * 8;
            float* pb = part + ((size_t)bid * 16 + k) * PART_K;
#pragma unroll
            for (int r = 0; r < 4; ++r) {
                int i = quad * 4 + r;
                int base = i * 32 - ((i * (i + 1)) >> 1);
                if (c >= i) pb[base + c] = q00[kk][r];            // upper diag quad
                pb[base + 16 + c] = q01[kk][r];                   // upper-right quad
                int i2 = 16 + i;
                if (c >= i) pb[i2 * 32 - ((i2 * (i2 + 1)) >> 1) + 16 + c] = q11[kk][r];
            }
            if (quad == 0) {
                pb[528 + c] = row0[kk];
                pb[528 + 16 + c] = row1[kk];
            }
            if (lane == 0) pb[560] = corner[kk];
        }
    }
}

// ---- merged reduce + solve: 256 blocks; group g reduces its slice of part
// (fresh via kernel boundary, plain loads) -> part2 via sc-stores; blocks g==0
// spin on cnt (R7-validated handshake) then solve via sc-loads of part2.
// SAFETY: 256 blocks x 256 thr = 1 block/CU -> all co-resident, spin cannot deadlock.
__global__ __launch_bounds__(256) void gmm_redsolve(const float* __restrict__ part,
                                                    float* __restrict__ part2,
                                                    int* __restrict__ cnt,
                                                    ushort_t* __restrict__ Wh,
                                                    ushort_t* __restrict__ Wl,
                                                    float* __restrict__ Bv,
                                                    float* __restrict__ Cc,
                                                    int N, int MB, int it) {
    int bid = (int)blockIdx.x;
    int t = threadIdx.x;
    int k = bid & 15, g = bid >> 4;
    int nb = (MB + RS - 1) / RS;
    int b0 = g * nb;
    int b1 = b0 + nb; if (b1 > MB) b1 = MB;

    for (int idx = t; idx < PART_K; idx += 256) {
        float s = 0.f;
#pragma unroll 4
        for (int b = b0; b < b1; ++b)
            s += part[((size_t)b * 16 + k) * PART_K + idx];
        STC(&part2[((size_t)g * 16 + k) * PART_K + idx], s);
    }
    __syncthreads();                 // drains vmcnt -> sc-stores complete
    if (t == 0)
        __hip_atomic_fetch_add(&cnt[it], 1, __ATOMIC_RELEASE, __HIP_MEMORY_SCOPE_AGENT);
    if (g != 0) return;

    // ---- solver (blocks 0..15): wait for all 256 groups, reduce part2, solve ----
    if (t == 0) {
        while (__hip_atomic_load(&cnt[it], __ATOMIC_ACQUIRE, __HIP_MEMORY_SCOPE_AGENT) < 256)
            __builtin_amdgcn_s_sleep(4);
    }
    __syncthreads();

    __shared__ float Ssh[561];
    __shared__ float Lsh[1056];     // 32x33
    __shared__ float Aish[1056];
    __shared__ float meansh[32];

    for (int idx = t; idx < PART_K; idx += 256) {
        float s = 0.f;
#pragma unroll
        for (int b = 0; b < RS; ++b)
            s += LDC(&part2[((size_t)b * 16 + k) * PART_K + idx]);
        Ssh[idx] = s;
    }
    __syncthreads();
    float nk = Ssh[560] + RESP_EPS;
    float inv = 1.f / nk;
    if (t < 32) meansh[t] = Ssh[528 + t] * inv;
    __syncthreads();
#pragma unroll
    for (int i0 = 0; i0 < 4; ++i0) {
        int i = i0 * 8 + (t >> 5), j = t & 31;
        int a = i < j ? i : j;
        int b2 = i < j ? j : i;
        float cv = Ssh[a * 32 - ((a * (a + 1)) >> 1) + b2];
        // M-step REGC + log_gauss REGC (reference applies both)
        Lsh[i * 33 + j] = cv * inv - meansh[i] * meansh[j] + ((i == j) ? 2.f * REGC : 0.f);
    }
    __syncthreads();
    // wave-synchronous Cholesky + triangular inverse (wave 0 only; R4/R5-validated)
    if (t < 64) {
#pragma unroll
        for (int j = 0; j < 32; ++j) {
            float s = Lsh[j * 33 + j];
#pragma unroll
            for (int p = 0; p < j; ++p) { float v = Lsh[j * 33 + p]; s -= v * v; }
            float dj = sqrtf(s);
            if (t > j && t < 32) {
                float s2 = Lsh[t * 33 + j];
#pragma unroll
                for (int p = 0; p < j; ++p) s2 -= Lsh[t * 33 + p] * Lsh[j * 33 + p];
                Lsh[t * 33 + j] = s2 / dj;
            }
            if (t == j) Lsh[j * 33 + j] = dj;
            asm volatile("" ::: "memory");
        }
        if (t < 32) {
            float ai[32];
#pragma unroll
            for (int r = 0; r < 32; ++r) {
                float s = (r == t) ? 1.f : 0.f;
#pragma unroll
                for (int p = 0; p < r; ++p) s -= Lsh[r * 33 + p] * ai[p];
                ai[r] = s / Lsh[r * 33 + r];
            }
#pragma unroll
            for (int r = 0; r < 32; ++r) Aish[r * 33 + t] = ai[r];
        }
    }
    __syncthreads();
#pragma unroll
    for (int i0 = 0; i0 < 4; ++i0) {
        int i = i0 * 8 + (t >> 5), j = t & 31;
        float v = Aish[i * 33 + j];
        ushort_t h = f2bf(v);
        Wh[(size_t)(k * 32 + i) * 32 + j] = h;
        Wl[(size_t)(k * 32 + i) * 32 + j] = f2bf(v - bf2f(h));
    }
    if (t < 32) {
        float s = 0.f;
#pragma unroll
        for (int j = 0; j < 32; ++j) s += Aish[t * 33 + j] * meansh[j];
        Bv[k * 32 + t] = s;
    }
    float lv = (t < 32) ? logf(Lsh[(t & 31) * 33 + (t & 31)]) : 0.f;
#pragma unroll
    for (int off = 1; off < 32; off <<= 1) lv += __shfl_xor(lv, off);
    if (t == 0) Cc[k] = logf(nk / (float)N) - 0.5f * 32.0f * LOG2PI - lv;
}

// ---------------- final estep: log-likelihood only (R3-validated) ----------------
__global__ __launch_bounds__(256, 2) void gmm_estep_fin(const ushort_t* __restrict__ Xh,
                                                        const ushort_t* __restrict__ Xl,
                                                        const ushort_t* __restrict__ Wh,
                                                        const ushort_t* __restrict__ Wl,
                                                        const float* __restrict__ Bv,
                                                        const float* __restrict__ Cc,
                                                        float* __restrict__ out,
                                                        int N) {
    int t = threadIdx.x;
    int wave = t >> 6, lane = t & 63;
    int quad = lane >> 4, c = lane & 15;
    int wstart = (blockIdx.x * 4 + wave) * 32;
    if (wstart + 32 > N) wstart = (N >= 32) ? (N - 32) : 0;
    bool al4 = ((N & 3) == 0);

    size_t xo0 = (size_t)(wstart + c) * 32 + quad * 8;
    size_t xo1 = (size_t)(wstart + 16 + c) * 32 + quad * 8;
    short8 ah0 = *(const short8*)(Xh + xo0);
    short8 al0 = *(const short8*)(Xl + xo0);
    short8 ah1 = *(const short8*)(Xh + xo1);
    short8 al1 = *(const short8*)(Xl + xo1);

    f32x4 p0[2], p1[2], p2[2], p3[2], fin[2];
#pragma unroll
    for (int k = 0; k < 16; ++k) {
        size_t w0 = (size_t)(k * 32 + c) * 32 + quad * 8;
        size_t w1 = w0 + 512;
        short8 bh0 = *(const short8*)(Wh + w0);
        short8 bl0 = *(const short8*)(Wl + w0);
        short8 bh1 = *(const short8*)(Wh + w1);
        short8 bl1 = *(const short8*)(Wl + w1);
        float bv0 = Bv[k * 32 + c];
        float bv1 = Bv[k * 32 + 16 + c];
#pragma unroll
        for (int tt = 0; tt < 2; ++tt) {
            short8 ah = tt ? ah1 : ah0;
            short8 al = tt ? al1 : al0;
            f32x4 a0 = {0.f, 0.f, 0.f, 0.f};
            f32x4 a1 = {0.f, 0.f, 0.f, 0.f};
            a0 = __builtin_amdgcn_mfma_f32_16x16x32_bf16(ah, bh0, a0, 0, 0, 0);
            a0 = __builtin_amdgcn_mfma_f32_16x16x32_bf16(ah, bl0, a0, 0, 0, 0);
            a0 = __builtin_amdgcn_mfma_f32_16x16x32_bf16(al, bh0, a0, 0, 0, 0);
            a1 = __builtin_amdgcn_mfma_f32_16x16x32_bf16(ah, bh1, a1, 0, 0, 0);
            a1 = __builtin_amdgcn_mfma_f32_16x16x32_bf16(ah, bl1, a1, 0, 0, 0);
            a1 = __builtin_amdgcn_mfma_f32_16x16x32_bf16(al, bh1, a1, 0, 0, 0);
            f32x4 ms;
#pragma unroll
            for (int r = 0; r < 4; ++r) {
                float d0 = a0[r] - bv0;
                float d1 = a1[r] - bv1;
                ms[r] = fmaf(d0, d0, d1 * d1);
            }
            if ((k & 1) == 0) { p0[tt] = ms; }
            else {
                f32x4 a = p0[tt] + shx4(p0[tt], 1);
                f32x4 b = ms + shx4(ms, 1);
                f32x4 v = sel4((c & 1) != 0, b, a);
                if ((k & 2) == 0) { p1[tt] = v; }
                else {
                    a = p1[tt] + shx4(p1[tt], 2); b = v + shx4(v, 2); v = sel4((c & 2) != 0, b, a);
                    if ((k & 4) == 0) { p2[tt] = v; }
                    else {
                        a = p2[tt] + shx4(p2[tt], 4); b = v + shx4(v, 4); v = sel4((c & 4) != 0, b, a);
                        if ((k & 8) == 0) { p3[tt] = v; }
                        else {
                            a = p3[tt] + shx4(p3[tt], 8); b = v + shx4(v, 8);
                            fin[tt] = sel4((c & 8) != 0, b, a);
                        }
                    }
                }
            }
        }
    }
    float ccv = Cc[c];
#pragma unroll
    for (int tt = 0; tt < 2; ++tt) {
        f32x4 lp;
#pragma unroll
        for (int r = 0; r < 4; ++r) lp[r] = ccv - 0.5f * fin[tt][r];
        f32x4 mx = lp;
#pragma unroll
        for (int off = 1; off < 16; off <<= 1) {
            f32x4 s = shx4(mx, off);
#pragma unroll
            for (int r = 0; r < 4; ++r) mx[r] = fmaxf(mx[r], s[r]);
        }
        f32x4 e;
#pragma unroll
        for (int r = 0; r < 4; ++r) e[r] = __expf(lp[r] - mx[r]);
        f32x4 sm = e;
#pragma unroll
        for (int off = 1; off < 16; off <<= 1) sm = sm + shx4(sm, off);
        if (c == 0) {
            int nb = wstart + tt * 16 + quad * 4;
            f32x4 o;
#pragma unroll
            for (int r = 0; r < 4; ++r) o[r] = mx[r] + __logf(sm[r]);
            if (al4) *(f32x4*)(out + nb) = o;
            else { for (int r = 0; r < 4; ++r) out[nb + r] = o[r]; }
        }
    }
}

// ================================== launcher ==================================
extern "C" void kernel_launch(void* const* d_in, const int* in_sizes, int n_in,
                              void* d_out, int out_size, void* d_ws, size_t ws_size,
                              hipStream_t stream) {
    const float* X   = (const float*)d_in[0];
    const float* w   = (const float*)d_in[1];
    const float* mu  = (const float*)d_in[2];
    const float* cov = (const float*)d_in[3];
    const int NITER = 5;
    int N = in_sizes[0] / 32;
    int MB = (N + 255) / 256;        // emstep blocks (256 samples each)
    int NCB = MB * 8;                // staged chunks (zero-padded past N)

    float* ws = (float*)d_ws;
    float*    Bv = ws;                               // 512
    float*    Cc = ws + 512;                         // 16 (+pad to 528)
    ushort_t* Wh = (ushort_t*)(ws + 528);            // 8192 f
    ushort_t* Wl = (ushort_t*)(ws + 8720);           // 8192 f -> 16912
    ushort_t* Xh = (ushort_t*)(ws + 16912);          // 16N f
    ushort_t* Xl = (ushort_t*)(ws + 16912 + (size_t)16 * N);
    size_t xt0 = 16912 + (size_t)32 * N;
    size_t XTHf = (size_t)NCB * 512;                 // XTH floats
    ushort_t* XTH = (ushort_t*)(ws + xt0);
    float*  part2 = ws + xt0 + XTHf;                 // RS*16*PART_K floats
    float*  part  = part2 + (size_t)RS * 16 * PART_K;// MB*16*PART_K floats
    int*    cnt   = (int*)(part + (size_t)MB * 16 * PART_K);  // 8 ints

    float* out = (float*)d_out;

    int eblocks = ((N + 31) / 32 + 3) / 4;

    gmm_prep<<<NCB + 16, 256, 0, stream>>>(X, w, mu, cov, Xh, Xl, XTH, Wh, Wl,
                                           Bv, Cc, cnt, N, NCB);

    for (int it = 0; it < NITER; ++it) {
        gmm_emstep<<<MB, 512, 0, stream>>>(Xh, Xl, XTH, Wh, Wl, Bv, Cc, part, N);
        gmm_redsolve<<<256, 256, 0, stream>>>(part, part2, cnt, Wh, Wl, Bv, Cc,
                                              N, MB, it);
    }
    gmm_estep_fin<<<eblocks, 256, 0, stream>>>(Xh, Xl, Wh, Wl, Bv, Cc, out, N);
}

// Round 10
// 455.493 us; speedup vs baseline: 1.6708x; 1.0226x over previous
//
#include <hip/hip_runtime.h>
#include <math.h>

#define REGC 1e-6f
#define LOG2PI 1.83787706640934534f
#define RESP_EPS 1.1920929e-6f

#define PART_K 561                  // packed upper-tri 528 + rows 32 + corner 1
#define RS 16                       // reduce groups

typedef __attribute__((ext_vector_type(8))) short short8;
typedef __attribute__((ext_vector_type(4))) float f32x4;
typedef unsigned short ushort_t;
typedef unsigned int uint_t;

// device-scope coherent ops — ONLY for the tiny part2/cnt handoff (0.57 MB).
#define STC(p, v) __hip_atomic_store((p), (v), __ATOMIC_RELAXED, __HIP_MEMORY_SCOPE_AGENT)
#define LDC(p)    __hip_atomic_load((p), __ATOMIC_RELAXED, __HIP_MEMORY_SCOPE_AGENT)

__device__ __forceinline__ ushort_t f2bf(float x) {
    uint_t u = __float_as_uint(x);
    uint_t r = (u + 0x7fffu + ((u >> 16) & 1u)) >> 16;   // RNE
    return (ushort_t)r;
}
__device__ __forceinline__ float bf2f(ushort_t h) {
    return __uint_as_float(((uint_t)h) << 16);
}
__device__ __forceinline__ f32x4 shx4(f32x4 v, int m) {
    f32x4 r;
#pragma unroll
    for (int i = 0; i < 4; ++i) r[i] = __shfl_xor(v[i], m);
    return r;
}
__device__ __forceinline__ f32x4 sel4(bool s, f32x4 b, f32x4 a) {
    f32x4 r;
#pragma unroll
    for (int i = 0; i < 4; ++i) r[i] = s ? b[i] : a[i];
    return r;
}
// r*x -> bf16 (round-half-up) packed A-frag; accumulates row sum.
__device__ __forceinline__ short8 pack_rx(const float* r8, const short8 bh, float& row) {
    uint_t u[8];
#pragma unroll
    for (int jj = 0; jj < 8; ++jj) {
        float av = r8[jj] * bf2f((ushort_t)bh[jj]);
        row += av;
        u[jj] = __float_as_uint(av) + 0x8000u;
    }
    short8 out;
    uint_t* o = (uint_t*)&out;
    o[0] = __builtin_amdgcn_perm(u[1], u[0], 0x07060302);
    o[1] = __builtin_amdgcn_perm(u[3], u[2], 0x07060302);
    o[2] = __builtin_amdgcn_perm(u[5], u[4], 0x07060302);
    o[3] = __builtin_amdgcn_perm(u[7], u[6], 0x07060302);
    return out;
}

// ---- fused prep: blocks [0,NCB) = xsplit; blocks [NCB,NCB+16) = prep0 + cnt zero ----
__global__ __launch_bounds__(256) void gmm_prep(const float* __restrict__ X,
                                                const float* __restrict__ w,
                                                const float* __restrict__ mu,
                                                const float* __restrict__ cov,
                                                ushort_t* __restrict__ Xh,
                                                ushort_t* __restrict__ Xl,
                                                ushort_t* __restrict__ XTH,
                                                ushort_t* __restrict__ Wh,
                                                ushort_t* __restrict__ Wl,
                                                float* __restrict__ Bv,
                                                float* __restrict__ Cc,
                                                int* __restrict__ cnt,
                                                int N, int NCB) {
    int t = threadIdx.x;
    if ((int)blockIdx.x < NCB) {
        // ---------------- xsplit body (R0-validated) ----------------
        int chunk = blockIdx.x;
        __shared__ float xsh[32][33];
        int s = t >> 3, q = t & 7;
        int n = chunk * 32 + s;
        float4 v = make_float4(0.f, 0.f, 0.f, 0.f);
        if (n < N) v = ((const float4*)(X + (size_t)n * 32))[q];
        float vv[4] = { v.x, v.y, v.z, v.w };
        xsh[s][q * 4 + 0] = v.x; xsh[s][q * 4 + 1] = v.y;
        xsh[s][q * 4 + 2] = v.z; xsh[s][q * 4 + 3] = v.w;
        if (n < N) {
            ushort_t h[4], l[4];
#pragma unroll
            for (int i = 0; i < 4; ++i) {
                h[i] = f2bf(vv[i]);
                l[i] = f2bf(vv[i] - bf2f(h[i]));
            }
            size_t o = (size_t)n * 32 + q * 4;
            *(uint2*)(Xh + o) = make_uint2((uint_t)h[0] | ((uint_t)h[1] << 16),
                                           (uint_t)h[2] | ((uint_t)h[3] << 16));
            *(uint2*)(Xl + o) = make_uint2((uint_t)l[0] | ((uint_t)l[1] << 16),
                                           (uint_t)l[2] | ((uint_t)l[3] << 16));
        }
        __syncthreads();
        int di = t >> 7;
        int lane = (t >> 1) & 63;
        int jj0 = (t & 1) * 4;
        int c = lane & 15, quad = lane >> 4;
        int d = di * 16 + c;
        ushort_t fh[4];
#pragma unroll
        for (int i = 0; i < 4; ++i) fh[i] = f2bf(xsh[quad * 8 + jj0 + i][d]);
        size_t fo = ((size_t)(chunk * 2 + di) * 64 + lane) * 8 + jj0;
        *(uint2*)(XTH + fo) = make_uint2((uint_t)fh[0] | ((uint_t)fh[1] << 16),
                                         (uint_t)fh[2] | ((uint_t)fh[3] << 16));
        return;
    }
    // ---------------- prep0 body (wave-synchronous, R5-validated) + cnt zero ----
    int k = (int)blockIdx.x - NCB;
    __shared__ float L[32][33];
    __shared__ float Ai[32][33];
    if (t >= 64) {
        if (k == 0 && t - 64 < 8) cnt[t - 64] = 0;   // ws may be poisoned
        return;
    }
    const float* cv = cov + (size_t)k * 1024;
    const float* muk = mu + (size_t)k * 32;
#pragma unroll
    for (int rep = 0; rep < 16; ++rep) {
        int idx = rep * 64 + t;
        int i = idx >> 5, j = idx & 31;
        L[i][j] = cv[idx] + (i == j ? REGC : 0.f);
    }
    asm volatile("" ::: "memory");
#pragma unroll
    for (int j = 0; j < 32; ++j) {
        float s = L[j][j];
#pragma unroll
        for (int p = 0; p < j; ++p) { float v = L[j][p]; s -= v * v; }
        float dj = sqrtf(s);
        if (t > j && t < 32) {
            float s2 = L[t][j];
#pragma unroll
            for (int p = 0; p < j; ++p) s2 -= L[t][p] * L[j][p];
            L[t][j] = s2 / dj;
        }
        if (t == j) L[j][j] = dj;
        asm volatile("" ::: "memory");
    }
    if (t < 32) {
        float ai[32];
#pragma unroll
        for (int r = 0; r < 32; ++r) {
            float s = (r == t) ? 1.f : 0.f;
#pragma unroll
            for (int p = 0; p < r; ++p) s -= L[r][p] * ai[p];
            ai[r] = s / L[r][r];
        }
#pragma unroll
        for (int r = 0; r < 32; ++r) Ai[r][t] = ai[r];
    }
    asm volatile("" ::: "memory");
#pragma unroll
    for (int rep = 0; rep < 16; ++rep) {
        int idx = rep * 64 + t;
        int i = idx >> 5, j = idx & 31;
        float v = Ai[i][j];
        ushort_t h = f2bf(v);
        Wh[(size_t)(k * 32 + i) * 32 + j] = h;
        Wl[(size_t)(k * 32 + i) * 32 + j] = f2bf(v - bf2f(h));
    }
    if (t < 32) {
        float s = 0.f;
#pragma unroll
        for (int j = 0; j < 32; ++j) s += Ai[t][j] * muk[j];
        Bv[k * 32 + t] = s;
    }
    float wsum = 0.f;
#pragma unroll
    for (int i = 0; i < 16; ++i) wsum += w[i];
    float lv = (t < 32) ? logf(L[t & 31][t & 31]) : 0.f;
#pragma unroll
    for (int off = 1; off < 32; off <<= 1) lv += __shfl_xor(lv, off);
    if (t == 0) Cc[k] = logf(w[k] / wsum) - 0.5f * 32.0f * LOG2PI - lv;
}

// ------- fused estep+moment: R3 body + source-level prefetch ------------------
// XTH (phase-2 frags) issued before phase 1; W double-buffered across k-iters.
__global__ __launch_bounds__(512)
void gmm_emstep(const ushort_t* __restrict__ Xh, const ushort_t* __restrict__ Xl,
                const ushort_t* __restrict__ XTH,
                const ushort_t* __restrict__ Wh, const ushort_t* __restrict__ Wl,
                const float* __restrict__ Bv, const float* __restrict__ Cc,
                float* __restrict__ part, int N) {
    __shared__ float rsh[16][260];
    int t = threadIdx.x;
    int wave = t >> 6, lane = t & 63;
    int quad = lane >> 4, c = lane & 15;
    int bid = (int)blockIdx.x;

    int wstart0 = bid * 256 + wave * 32;
    bool dup = (wstart0 + 32 > N);
    int wst = dup ? ((N >= 32) ? N - 32 : 0) : wstart0;

    size_t xo0 = (size_t)(wst + c) * 32 + quad * 8;
    size_t xo1 = (size_t)(wst + 16 + c) * 32 + quad * 8;
    short8 ah0 = *(const short8*)(Xh + xo0);
    short8 al0 = *(const short8*)(Xl + xo0);
    short8 ah1 = *(const short8*)(Xh + xo1);
    short8 al1 = *(const short8*)(Xl + xo1);

    // ---- prefetch phase-2 XTH fragments (in flight across all of phase 1) ----
    short8 xt0[8], xt1[8];
#pragma unroll
    for (int ch = 0; ch < 8; ++ch) {
        size_t fb = (((size_t)(bid * 8 + ch)) * 128 + lane) * 8;
        xt0[ch] = *(const short8*)(XTH + fb);        // dims 0-15 frag
        xt1[ch] = *(const short8*)(XTH + fb + 512);  // dims 16-31 frag
    }

    // ---- phase 1: estep (R0/R3-validated math, W reg-double-buffered) ----
    {
        f32x4 p0[2], p1[2], p2[2], p3[2], fin[2];
        size_t wb0 = (size_t)c * 32 + quad * 8;      // k = 0
        short8 nbh0 = *(const short8*)(Wh + wb0);
        short8 nbl0 = *(const short8*)(Wl + wb0);
        short8 nbh1 = *(const short8*)(Wh + wb0 + 512);
        short8 nbl1 = *(const short8*)(Wl + wb0 + 512);
#pragma unroll
        for (int k = 0; k < 16; ++k) {
            short8 bh0 = nbh0, bl0 = nbl0, bh1 = nbh1, bl1 = nbl1;
            if (k < 15) {                            // static: loop fully unrolled
                size_t wn = (size_t)((k + 1) * 32 + c) * 32 + quad * 8;
                nbh0 = *(const short8*)(Wh + wn);
                nbl0 = *(const short8*)(Wl + wn);
                nbh1 = *(const short8*)(Wh + wn + 512);
                nbl1 = *(const short8*)(Wl + wn + 512);
            }
            float bv0 = Bv[k * 32 + c];
            float bv1 = Bv[k * 32 + 16 + c];
#pragma unroll
            for (int tt = 0; tt < 2; ++tt) {
                short8 ah = tt ? ah1 : ah0;
                short8 al = tt ? al1 : al0;
                f32x4 a0 = {0.f, 0.f, 0.f, 0.f};
                f32x4 a1 = {0.f, 0.f, 0.f, 0.f};
                a0 = __builtin_amdgcn_mfma_f32_16x16x32_bf16(ah, bh0, a0, 0, 0, 0);
                a0 = __builtin_amdgcn_mfma_f32_16x16x32_bf16(ah, bl0, a0, 0, 0, 0);
                a0 = __builtin_amdgcn_mfma_f32_16x16x32_bf16(al, bh0, a0, 0, 0, 0);
                a1 = __builtin_amdgcn_mfma_f32_16x16x32_bf16(ah, bh1, a1, 0, 0, 0);
                a1 = __builtin_amdgcn_mfma_f32_16x16x32_bf16(ah, bl1, a1, 0, 0, 0);
                a1 = __builtin_amdgcn_mfma_f32_16x16x32_bf16(al, bh1, a1, 0, 0, 0);
                f32x4 ms;
#pragma unroll
                for (int r = 0; r < 4; ++r) {
                    float d0 = a0[r] - bv0;
                    float d1 = a1[r] - bv1;
                    ms[r] = fmaf(d0, d0, d1 * d1);
                }
                if ((k & 1) == 0) { p0[tt] = ms; }
                else {
                    f32x4 a = p0[tt] + shx4(p0[tt], 1);
                    f32x4 b = ms + shx4(ms, 1);
                    f32x4 v = sel4((c & 1) != 0, b, a);
                    if ((k & 2) == 0) { p1[tt] = v; }
                    else {
                        a = p1[tt] + shx4(p1[tt], 2); b = v + shx4(v, 2); v = sel4((c & 2) != 0, b, a);
                        if ((k & 4) == 0) { p2[tt] = v; }
                        else {
                            a = p2[tt] + shx4(p2[tt], 4); b = v + shx4(v, 4); v = sel4((c & 4) != 0, b, a);
                            if ((k & 8) == 0) { p3[tt] = v; }
                            else {
                                a = p3[tt] + shx4(p3[tt], 8); b = v + shx4(v, 8);
                                fin[tt] = sel4((c & 8) != 0, b, a);
                            }
                        }
                    }
                }
            }
        }
        float ccv = Cc[c];
#pragma unroll
        for (int tt = 0; tt < 2; ++tt) {
            f32x4 lp;
#pragma unroll
            for (int r = 0; r < 4; ++r) lp[r] = ccv - 0.5f * fin[tt][r];
            f32x4 mx = lp;
#pragma unroll
            for (int off = 1; off < 16; off <<= 1) {
                f32x4 s = shx4(mx, off);
#pragma unroll
                for (int r = 0; r < 4; ++r) mx[r] = fmaxf(mx[r], s[r]);
            }
            f32x4 e;
#pragma unroll
            for (int r = 0; r < 4; ++r) e[r] = __expf(lp[r] - mx[r]);
            f32x4 sm = e;
#pragma unroll
            for (int off = 1; off < 16; off <<= 1) sm = sm + shx4(sm, off);
            f32x4 sv;
#pragma unroll
            for (int r = 0; r < 4; ++r) sv[r] = dup ? 0.f : e[r] / sm[r];
            *(f32x4*)&rsh[c][wave * 32 + tt * 16 + quad * 4] = sv;
        }
    }
    __syncthreads();

    // ---- phase 2: moment (wave = 2 comps, 8 chunks, sym-packed, reg frags) ----
    {
        f32x4 q00[2], q01[2], q11[2];
#pragma unroll
        for (int kk = 0; kk < 2; ++kk) {
            q00[kk] = (f32x4){0.f, 0.f, 0.f, 0.f};
            q01[kk] = (f32x4){0.f, 0.f, 0.f, 0.f};
            q11[kk] = (f32x4){0.f, 0.f, 0.f, 0.f};
        }
        float row0[2] = {0.f, 0.f}, row1[2] = {0.f, 0.f}, corner[2] = {0.f, 0.f};

#pragma unroll
        for (int ch = 0; ch < 8; ++ch) {
            short8 bh0 = xt0[ch];
            short8 bh1 = xt1[ch];
#pragma unroll
            for (int kk = 0; kk < 2; ++kk) {
                int k = wave + kk * 8;
                float r8[8];
#pragma unroll
                for (int jj = 0; jj < 8; ++jj) r8[jj] = rsh[k][ch * 32 + quad * 8 + jj];
                corner[kk] += ((r8[0] + r8[1]) + (r8[2] + r8[3])) +
                              ((r8[4] + r8[5]) + (r8[6] + r8[7]));
                short8 a0 = pack_rx(r8, bh0, row0[kk]);
                short8 a1 = pack_rx(r8, bh1, row1[kk]);
                q00[kk] = __builtin_amdgcn_mfma_f32_16x16x32_bf16(a0, bh0, q00[kk], 0, 0, 0);
                q01[kk] = __builtin_amdgcn_mfma_f32_16x16x32_bf16(a0, bh1, q01[kk], 0, 0, 0);
                q11[kk] = __builtin_amdgcn_mfma_f32_16x16x32_bf16(a1, bh1, q11[kk], 0, 0, 0);
                // m10 dropped: symmetric, reconstructed from q01 in redsolve.
            }
        }
#pragma unroll
        for (int kk = 0; kk < 2; ++kk) {
            row0[kk] += __shfl_xor(row0[kk], 16);  row0[kk] += __shfl_xor(row0[kk], 32);
            row1[kk] += __shfl_xor(row1[kk], 16);  row1[kk] += __shfl_xor(row1[kk], 32);
            corner[kk] += __shfl_xor(corner[kk], 16);  corner[kk] += __shfl_xor(corner[kk], 32);

            int k = wave + kk * 8;
            float* pb = part + ((size_t)bid * 16 + k) * PART_K;
#pragma unroll
            for (int r = 0; r < 4; ++r) {
                int i = quad * 4 + r;
                int base = i * 32 - ((i * (i + 1)) >> 1);
                if (c >= i) pb[base + c] = q00[kk][r];            // upper diag quad
                pb[base + 16 + c] = q01[kk][r];                   // upper-right quad
                int i2 = 16 + i;
                if (c >= i) pb[i2 * 32 - ((i2 * (i2 + 1)) >> 1) + 16 + c] = q11[kk][r];
            }
            if (quad == 0) {
                pb[528 + c] = row0[kk];
                pb[528 + 16 + c] = row1[kk];
            }
            if (lane == 0) pb[560] = corner[kk];
        }
    }
}

// ---- merged reduce + solve (R9-validated): group g reduces its slice of part
// (fresh via kernel boundary, plain loads) -> part2 via sc-stores; blocks g==0
// spin on cnt (R7-validated handshake) then solve via sc-loads of part2.
// SAFETY: 256 blocks x 256 thr = 1 block/CU -> all co-resident, spin cannot deadlock.
__global__ __launch_bounds__(256) void gmm_redsolve(const float* __restrict__ part,
                                                    float* __restrict__ part2,
                                                    int* __restrict__ cnt,
                                                    ushort_t* __restrict__ Wh,
                                                    ushort_t* __restrict__ Wl,
                                                    float* __restrict__ Bv,
                                                    float* __restrict__ Cc,
                                                    int N, int MB, int it) {
    int bid = (int)blockIdx.x;
    int t = threadIdx.x;
    int k = bid & 15, g = bid >> 4;
    int nb = (MB + RS - 1) / RS;
    int b0 = g * nb;
    int b1 = b0 + nb; if (b1 > MB) b1 = MB;

    for (int idx = t; idx < PART_K; idx += 256) {
        float s = 0.f;
#pragma unroll 4
        for (int b = b0; b < b1; ++b)
            s += part[((size_t)b * 16 + k) * PART_K + idx];
        STC(&part2[((size_t)g * 16 + k) * PART_K + idx], s);
    }
    __syncthreads();                 // drains vmcnt -> sc-stores complete
    if (t == 0)
        __hip_atomic_fetch_add(&cnt[it], 1, __ATOMIC_RELEASE, __HIP_MEMORY_SCOPE_AGENT);
    if (g != 0) return;

    // ---- solver (blocks 0..15): wait for all 256 groups, reduce part2, solve ----
    if (t == 0) {
        while (__hip_atomic_load(&cnt[it], __ATOMIC_ACQUIRE, __HIP_MEMORY_SCOPE_AGENT) < 256)
            __builtin_amdgcn_s_sleep(4);
    }
    __syncthreads();

    __shared__ float Ssh[561];
    __shared__ float Lsh[1056];     // 32x33
    __shared__ float Aish[1056];
    __shared__ float meansh[32];

    for (int idx = t; idx < PART_K; idx += 256) {
        float s = 0.f;
#pragma unroll
        for (int b = 0; b < RS; ++b)
            s += LDC(&part2[((size_t)b * 16 + k) * PART_K + idx]);
        Ssh[idx] = s;
    }
    __syncthreads();
    float nk = Ssh[560] + RESP_EPS;
    float inv = 1.f / nk;
    if (t < 32) meansh[t] = Ssh[528 + t] * inv;
    __syncthreads();
#pragma unroll
    for (int i0 = 0; i0 < 4; ++i0) {
        int i = i0 * 8 + (t >> 5), j = t & 31;
        int a = i < j ? i : j;
        int b2 = i < j ? j : i;
        float cv = Ssh[a * 32 - ((a * (a + 1)) >> 1) + b2];
        // M-step REGC + log_gauss REGC (reference applies both)
        Lsh[i * 33 + j] = cv * inv - meansh[i] * meansh[j] + ((i == j) ? 2.f * REGC : 0.f);
    }
    __syncthreads();
    // wave-synchronous Cholesky + triangular inverse (wave 0 only; R4/R5-validated)
    if (t < 64) {
#pragma unroll
        for (int j = 0; j < 32; ++j) {
            float s = Lsh[j * 33 + j];
#pragma unroll
            for (int p = 0; p < j; ++p) { float v = Lsh[j * 33 + p]; s -= v * v; }
            float dj = sqrtf(s);
            if (t > j && t < 32) {
                float s2 = Lsh[t * 33 + j];
#pragma unroll
                for (int p = 0; p < j; ++p) s2 -= Lsh[t * 33 + p] * Lsh[j * 33 + p];
                Lsh[t * 33 + j] = s2 / dj;
            }
            if (t == j) Lsh[j * 33 + j] = dj;
            asm volatile("" ::: "memory");
        }
        if (t < 32) {
            float ai[32];
#pragma unroll
            for (int r = 0; r < 32; ++r) {
                float s = (r == t) ? 1.f : 0.f;
#pragma unroll
                for (int p = 0; p < r; ++p) s -= Lsh[r * 33 + p] * ai[p];
                ai[r] = s / Lsh[r * 33 + r];
            }
#pragma unroll
            for (int r = 0; r < 32; ++r) Aish[r * 33 + t] = ai[r];
        }
    }
    __syncthreads();
#pragma unroll
    for (int i0 = 0; i0 < 4; ++i0) {
        int i = i0 * 8 + (t >> 5), j = t & 31;
        float v = Aish[i * 33 + j];
        ushort_t h = f2bf(v);
        Wh[(size_t)(k * 32 + i) * 32 + j] = h;
        Wl[(size_t)(k * 32 + i) * 32 + j] = f2bf(v - bf2f(h));
    }
    if (t < 32) {
        float s = 0.f;
#pragma unroll
        for (int j = 0; j < 32; ++j) s += Aish[t * 33 + j] * meansh[j];
        Bv[k * 32 + t] = s;
    }
    float lv = (t < 32) ? logf(Lsh[(t & 31) * 33 + (t & 31)]) : 0.f;
#pragma unroll
    for (int off = 1; off < 32; off <<= 1) lv += __shfl_xor(lv, off);
    if (t == 0) Cc[k] = logf(nk / (float)N) - 0.5f * 32.0f * LOG2PI - lv;
}

// ---------------- final estep: log-likelihood only (R3-validated) ----------------
__global__ __launch_bounds__(256, 2) void gmm_estep_fin(const ushort_t* __restrict__ Xh,
                                                        const ushort_t* __restrict__ Xl,
                                                        const ushort_t* __restrict__ Wh,
                                                        const ushort_t* __restrict__ Wl,
                                                        const float* __restrict__ Bv,
                                                        const float* __restrict__ Cc,
                                                        float* __restrict__ out,
                                                        int N) {
    int t = threadIdx.x;
    int wave = t >> 6, lane = t & 63;
    int quad = lane >> 4, c = lane & 15;
    int wstart = (blockIdx.x * 4 + wave) * 32;
    if (wstart + 32 > N) wstart = (N >= 32) ? (N - 32) : 0;
    bool al4 = ((N & 3) == 0);

    size_t xo0 = (size_t)(wstart + c) * 32 + quad * 8;
    size_t xo1 = (size_t)(wstart + 16 + c) * 32 + quad * 8;
    short8 ah0 = *(const short8*)(Xh + xo0);
    short8 al0 = *(const short8*)(Xl + xo0);
    short8 ah1 = *(const short8*)(Xh + xo1);
    short8 al1 = *(const short8*)(Xl + xo1);

    f32x4 p0[2], p1[2], p2[2], p3[2], fin[2];
#pragma unroll
    for (int k = 0; k < 16; ++k) {
        size_t w0 = (size_t)(k * 32 + c) * 32 + quad * 8;
        size_t w1 = w0 + 512;
        short8 bh0 = *(const short8*)(Wh + w0);
        short8 bl0 = *(const short8*)(Wl + w0);
        short8 bh1 = *(const short8*)(Wh + w1);
        short8 bl1 = *(const short8*)(Wl + w1);
        float bv0 = Bv[k * 32 + c];
        float bv1 = Bv[k * 32 + 16 + c];
#pragma unroll
        for (int tt = 0; tt < 2; ++tt) {
            short8 ah = tt ? ah1 : ah0;
            short8 al = tt ? al1 : al0;
            f32x4 a0 = {0.f, 0.f, 0.f, 0.f};
            f32x4 a1 = {0.f, 0.f, 0.f, 0.f};
            a0 = __builtin_amdgcn_mfma_f32_16x16x32_bf16(ah, bh0, a0, 0, 0, 0);
            a0 = __builtin_amdgcn_mfma_f32_16x16x32_bf16(ah, bl0, a0, 0, 0, 0);
            a0 = __builtin_amdgcn_mfma_f32_16x16x32_bf16(al, bh0, a0, 0, 0, 0);
            a1 = __builtin_amdgcn_mfma_f32_16x16x32_bf16(ah, bh1, a1, 0, 0, 0);
            a1 = __builtin_amdgcn_mfma_f32_16x16x32_bf16(ah, bl1, a1, 0, 0, 0);
            a1 = __builtin_amdgcn_mfma_f32_16x16x32_bf16(al, bh1, a1, 0, 0, 0);
            f32x4 ms;
#pragma unroll
            for (int r = 0; r < 4; ++r) {
                float d0 = a0[r] - bv0;
                float d1 = a1[r] - bv1;
                ms[r] = fmaf(d0, d0, d1 * d1);
            }
            if ((k & 1) == 0) { p0[tt] = ms; }
            else {
                f32x4 a = p0[tt] + shx4(p0[tt], 1);
                f32x4 b = ms + shx4(ms, 1);
                f32x4 v = sel4((c & 1) != 0, b, a);
                if ((k & 2) == 0) { p1[tt] = v; }
                else {
                    a = p1[tt] + shx4(p1[tt], 2); b = v + shx4(v, 2); v = sel4((c & 2) != 0, b, a);
                    if ((k & 4) == 0) { p2[tt] = v; }
                    else {
                        a = p2[tt] + shx4(p2[tt], 4); b = v + shx4(v, 4); v = sel4((c & 4) != 0, b, a);
                        if ((k & 8) == 0) { p3[tt] = v; }
                        else {
                            a = p3[tt] + shx4(p3[tt], 8); b = v + shx4(v, 8);
                            fin[tt] = sel4((c & 8) != 0, b, a);
                        }
                    }
                }
            }
        }
    }
    float ccv = Cc[c];
#pragma unroll
    for (int tt = 0; tt < 2; ++tt) {
        f32x4 lp;
#pragma unroll
        for (int r = 0; r < 4; ++r) lp[r] = ccv - 0.5f * fin[tt][r];
        f32x4 mx = lp;
#pragma unroll
        for (int off = 1; off < 16; off <<= 1) {
            f32x4 s = shx4(mx, off);
#pragma unroll
            for (int r = 0; r < 4; ++r) mx[r] = fmaxf(mx[r], s[r]);
        }
        f32x4 e;
#pragma unroll
        for (int r = 0; r < 4; ++r) e[r] = __expf(lp[r] - mx[r]);
        f32x4 sm = e;
#pragma unroll
        for (int off = 1; off < 16; off <<= 1) sm = sm + shx4(sm, off);
        if (c == 0) {
            int nb = wstart + tt * 16 + quad * 4;
            f32x4 o;
#pragma unroll
            for (int r = 0; r < 4; ++r) o[r] = mx[r] + __logf(sm[r]);
            if (al4) *(f32x4*)(out + nb) = o;
            else { for (int r = 0; r < 4; ++r) out[nb + r] = o[r]; }
        }
    }
}

// ================================== launcher ==================================
extern "C" void kernel_launch(void* const* d_in, const int* in_sizes, int n_in,
                              void* d_out, int out_size, void* d_ws, size_t ws_size,
                              hipStream_t stream) {
    const float* X   = (const float*)d_in[0];
    const float* w   = (const float*)d_in[1];
    const float* mu  = (const float*)d_in[2];
    const float* cov = (const float*)d_in[3];
    const int NITER = 5;
    int N = in_sizes[0] / 32;
    int MB = (N + 255) / 256;        // emstep blocks (256 samples each)
    int NCB = MB * 8;                // staged chunks (zero-padded past N)

    float* ws = (float*)d_ws;
    float*    Bv = ws;                               // 512
    float*    Cc = ws + 512;                         // 16 (+pad to 528)
    ushort_t* Wh = (ushort_t*)(ws + 528);            // 8192 f
    ushort_t* Wl = (ushort_t*)(ws + 8720);           // 8192 f -> 16912
    ushort_t* Xh = (ushort_t*)(ws + 16912);          // 16N f
    ushort_t* Xl = (ushort_t*)(ws + 16912 + (size_t)16 * N);
    size_t xt0 = 16912 + (size_t)32 * N;
    size_t XTHf = (size_t)NCB * 512;                 // XTH floats
    ushort_t* XTH = (ushort_t*)(ws + xt0);
    float*  part2 = ws + xt0 + XTHf;                 // RS*16*PART_K floats
    float*  part  = part2 + (size_t)RS * 16 * PART_K;// MB*16*PART_K floats
    int*    cnt   = (int*)(part + (size_t)MB * 16 * PART_K);  // 8 ints

    float* out = (float*)d_out;

    int eblocks = ((N + 31) / 32 + 3) / 4;

    gmm_prep<<<NCB + 16, 256, 0, stream>>>(X, w, mu, cov, Xh, Xl, XTH, Wh, Wl,
                                           Bv, Cc, cnt, N, NCB);

    for (int it = 0; it < NITER; ++it) {
        gmm_emstep<<<MB, 512, 0, stream>>>(Xh, Xl, XTH, Wh, Wl, Bv, Cc, part, N);
        gmm_redsolve<<<256, 256, 0, stream>>>(part, part2, cnt, Wh, Wl, Bv, Cc,
                                              N, MB, it);
    }
    gmm_estep_fin<<<eblocks, 256, 0, stream>>>(Xh, Xl, Wh, Wl, Bv, Cc, out, N);
}